// Round 15
// baseline (134.894 us; speedup 1.0000x reference)
//
#include <hip/hip_runtime.h>
#include <hip/hip_cooperative_groups.h>
#include <stdint.h>
#include <math.h>

namespace cg = cooperative_groups;

// Problem constants
#define BATCH 4096
#define NT    8192          // 2*BATCH
#define FD    256           // feature dim
#define TM    256           // block tile rows (A side)
#define TN    128           // block tile cols (B side)
#define BK    32            // K chunk per staging step (8 steps, triple-buffered)
#define NUMK  5
#define NBLK  1056          // tiles (I,J) with J >= 2I; %8==0
#define PBLK  256           // prep blocks (32 rows each, 1024 threads)

typedef __attribute__((ext_vector_type(8))) short bf16x8;  // 8 bf16 = 4 VGPRs
typedef __attribute__((ext_vector_type(4))) float f32x4;

// ---- workspace layout (bytes) ----
// fb 4 MiB | sq 32 KiB | pcol 256 KiB | wsum 1 KiB | gamma 4 B
static const size_t WS_FB    = 0;
static const size_t WS_SQ    = (size_t)NT * FD * 2;              // 4194304
static const size_t WS_PCOL  = WS_SQ + (size_t)NT * 4;           // +32768
static const size_t WS_WSUM  = WS_PCOL + (size_t)PBLK * 256 * 4; // +256 KiB
static const size_t WS_GAMMA = WS_WSUM + (size_t)PBLK * 4;       // +1 KiB

__device__ __forceinline__ unsigned short f2bf_rne(float x) {
    unsigned u = __float_as_uint(x);
    unsigned r = (u + 0x7fffu + ((u >> 16) & 1u)) >> 16;
    return (unsigned short)r;
}

__device__ __forceinline__ void async_copy16(void* lds, const void* g) {
    __builtin_amdgcn_global_load_lds(
        (__attribute__((address_space(1))) void*)(void*)(const_cast<void*>(g)),
        (__attribute__((address_space(3))) void*)lds, 16, 0, 0);
}

// ---------------- kernel 1 (cooperative): prep + fused gamma tail -------------
// 256 blocks x 1024 threads = exactly 1 block/CU (co-resident). Phase 1: the
// r13 prep body (convert + row norms + per-block partials, NO atomics).
// grid.sync(). Phase 2: block 0 alone runs the r13 gamma reduction on the
// L2-hot 256 KiB partials (writes gamma, zeroes out); other blocks retire.
// Removes the separate mmd_gamma dispatch + one inter-node gap.
__global__ void mmd_prep_fused(const float* __restrict__ s_feat,
                               const float* __restrict__ t_feat,
                               unsigned short* __restrict__ fb,
                               float* __restrict__ sq,
                               float* __restrict__ pcol,
                               float* __restrict__ wsum,
                               float* __restrict__ gamma,
                               float* __restrict__ out) {
    __shared__ float cp[16][FD];
    __shared__ float rw[16];
    const int w    = threadIdx.x >> 6;           // 0..15
    const int lane = threadIdx.x & 63;
    float c0 = 0.f, c1 = 0.f, c2 = 0.f, c3 = 0.f;
    float wtot = 0.f;
#pragma unroll
    for (int t = 0; t < 2; ++t) {
        int row = blockIdx.x * 32 + w * 2 + t;
        const float* src = (row < BATCH) ? (s_feat + (size_t)row * FD)
                                         : (t_feat + (size_t)(row - BATCH) * FD);
        float4 v = ((const float4*)src)[lane];
        unsigned int u01 = (unsigned)f2bf_rne(v.x) | ((unsigned)f2bf_rne(v.y) << 16);
        unsigned int u23 = (unsigned)f2bf_rne(v.z) | ((unsigned)f2bf_rne(v.w) << 16);
        ((uint2*)(fb + (size_t)row * FD))[lane] = make_uint2(u01, u23);
        float ss = v.x * v.x + v.y * v.y + v.z * v.z + v.w * v.w;
        for (int off = 32; off; off >>= 1) ss += __shfl_down(ss, off);
        if (lane == 0) { sq[row] = ss; wtot += ss; }
        c0 += v.x; c1 += v.y; c2 += v.z; c3 += v.w;
    }
    cp[w][4 * lane + 0] = c0;
    cp[w][4 * lane + 1] = c1;
    cp[w][4 * lane + 2] = c2;
    cp[w][4 * lane + 3] = c3;
    if (lane == 0) rw[w] = wtot;
    __syncthreads();
    const int tid = threadIdx.x;
    if (tid < 256) {
        float s = 0.f;
#pragma unroll
        for (int k = 0; k < 16; ++k) s += cp[k][tid];
        pcol[(size_t)blockIdx.x * 256 + tid] = s;
    }
    if (tid == 0) {
        float s = 0.f;
#pragma unroll
        for (int k = 0; k < 16; ++k) s += rw[k];
        wsum[blockIdx.x] = s;
    }

    cg::this_grid().sync();   // pcol/wsum globally visible
    if (blockIdx.x != 0) return;

    // ---- gamma tail (r13 mmd_gamma body, 1024 threads of block 0) ----
    __shared__ float gcol[4][256];
    __shared__ float redc[4], redw[4];
    const int c = tid & 255, s = tid >> 8;       // s = 0..3
    float a0 = 0.f, a1 = 0.f, a2 = 0.f, a3 = 0.f;
#pragma unroll 4
    for (int k = 0; k < 64; k += 4) {
        a0 += pcol[(size_t)(s * 64 + k + 0) * 256 + c];
        a1 += pcol[(size_t)(s * 64 + k + 1) * 256 + c];
        a2 += pcol[(size_t)(s * 64 + k + 2) * 256 + c];
        a3 += pcol[(size_t)(s * 64 + k + 3) * 256 + c];
    }
    gcol[s][c] = (a0 + a1) + (a2 + a3);
    if (tid < 256) {
        float wv = wsum[tid];
        for (int off = 32; off; off >>= 1) wv += __shfl_down(wv, off);
        if (lane == 0) redw[tid >> 6] = wv;
    }
    __syncthreads();
    if (tid < 256) {
        float colv = (gcol[0][c] + gcol[1][c]) + (gcol[2][c] + gcol[3][c]);
        float cv2 = colv * colv;
        for (int off = 32; off; off >>= 1) cv2 += __shfl_down(cv2, off);
        if (lane == 0) redc[tid >> 6] = cv2;
    }
    __syncthreads();
    if (tid == 0) {
        float s2  = (redc[0] + redc[1]) + (redc[2] + redc[3]);
        float ssq = (redw[0] + redw[1]) + (redw[2] + redw[3]);
        // sum(distances) = 2*n*sum(sq) - 2*||colsum||^2 (clamp effect negligible)
        float sumd = 2.0f * (float)NT * ssq - 2.0f * s2;
        float n2n  = (float)((long long)NT * NT - NT);   // n^2 - n
        gamma[0]   = 0.25f * (n2n / sumd);   // bw / 2^(NUM_KERNELS//2)
        out[0]     = 0.f;                    // zero accumulator for mmd_main
    }
}

// ---------------- kernel 2: fused GEMM + gaussian-kernel + reduce ----------------
// Champion (r13), verbatim: 256x128 tiles, 512 threads (8 waves, 4Mx2N);
// triple-buffered BK=32 with counted vmcnt; gamma read as precomputed scalar.
__global__ __launch_bounds__(512, 4) void mmd_main(
    const unsigned short* __restrict__ fb,
    const float* __restrict__ sq,
    const float* __restrict__ gamma,
    float* __restrict__ out) {
    // XCD-chunked swizzle (NBLK % 8 == 0 -> bijective)
    const int bid = blockIdx.x;
    const int swz = (bid & 7) * (NBLK / 8) + (bid >> 3);
    // decode: I = largest i with C(i)=i*(65-i) <= swz ; J = 2I + (swz - C(I))
    int I = (int)((65.0f - sqrtf(fmaxf(4225.0f - 4.0f * (float)swz, 0.f))) * 0.5f);
    if (I > 31) I = 31;
    while (I > 0 && I * (65 - I) > swz) --I;
    while (I < 31 && (I + 1) * (65 - (I + 1)) <= swz) ++I;
    const int J = 2 * I + (swz - I * (65 - I));
    const bool straddle = ((J >> 1) == I);   // tile touches the diagonal

    __shared__ __align__(16) unsigned short a_t[3][TM * BK];  // 3 x 16 KiB
    __shared__ __align__(16) unsigned short b_t[3][TN * BK];  // 3 x 8 KiB
    __shared__ float sqa[TM], sqb[TN];
    __shared__ float red[8];

    const int tid  = threadIdx.x;
    const int w    = tid >> 6, lane = tid & 63;
    const int wm2  = w >> 1, wn2 = w & 1;        // 4x2 waves over 256x128
    const int quad = lane >> 4, m16 = lane & 15;
    const int lrow16 = lane >> 2;                // 0..15 (row within 16-row group)
    const int pslot  = lane & 3;                 // physical 16B slot within 64B row

    const size_t rowA0 = (size_t)I * TM;
    const size_t rowB0 = (size_t)J * TN;

    // oldest loads first: sq + gamma (consumed pre-loop)
    float sqv = 0.f;
    if (tid < TM)                sqv = sq[rowA0 + tid];
    else if (tid < TM + TN)      sqv = sq[rowB0 + (tid - TM)];
    const float g0 = gamma[0];

    // Swizzle: physical slot p of row r holds global chunk p ^ ((r>>1)&3).
#define STAGE(buf, k0_) do {                                                   \
        _Pragma("unroll")                                                      \
        for (int q = 0; q < 2; ++q) {                                          \
            int rr_ = w * 32 + q * 16 + lrow16;   /* 0..255 */                 \
            int gc_ = pslot ^ ((rr_ >> 1) & 3);                                \
            async_copy16(&a_t[buf][(w * 32 + q * 16) * BK],                    \
                         fb + (rowA0 + rr_) * FD + (k0_) + gc_ * 8);           \
        }                                                                      \
        {                                                                      \
            int rr_ = w * 16 + lrow16;            /* 0..127 */                 \
            int gc_ = pslot ^ ((rr_ >> 1) & 3);                                \
            async_copy16(&b_t[buf][(w * 16) * BK],                             \
                         fb + (rowB0 + rr_) * FD + (k0_) + gc_ * 8);           \
        }                                                                      \
    } while (0)

    // prologue: fill buffers 0..2 (drained by the single __syncthreads below)
    STAGE(0, 0);
    STAGE(1, BK);
    STAGE(2, 2 * BK);

    if (tid < TM)                sqa[tid] = sqv;
    else if (tid < TM + TN)      sqb[tid - TM] = sqv;

    const f32x4 fzero = {0.f, 0.f, 0.f, 0.f};
    f32x4 acc[4][4];
#pragma unroll
    for (int a = 0; a < 4; ++a)
#pragma unroll
        for (int b = 0; b < 4; ++b) acc[a][b] = fzero;

    __syncthreads();   // full drain once: chunks 0-2 resident, sqa/sqb visible

#pragma unroll
    for (int st = 0; st < 8; ++st) {
        if (st > 0) {
            if (st >= 3) {
                // certify chunk st (staged at step st-2); keep st-1's 3 loads
                // in flight. At st=7 nothing newer is outstanding.
                if (st == 7) asm volatile("s_waitcnt vmcnt(0)" ::: "memory");
                else         asm volatile("s_waitcnt vmcnt(3)" ::: "memory");
            }
            __builtin_amdgcn_s_barrier();        // publish buf; frees buf (st-1)%3
            __builtin_amdgcn_sched_barrier(0);
            // stage chunk st+2 into the buffer freed by this barrier
            if (st <= 5) STAGE((st + 2) % 3, (st + 2) * BK);
        }
        const int cur = st % 3;   // compile-time after full unroll

        bf16x8 af[4], bf[4];
#pragma unroll
        for (int tm = 0; tm < 4; ++tm) {
            int row = wm2 * 64 + tm * 16 + m16;
            int p = quad ^ ((row >> 1) & 3);
            af[tm] = *(const bf16x8*)&a_t[cur][row * BK + p * 8];
        }
#pragma unroll
        for (int tn = 0; tn < 4; ++tn) {
            int row = wn2 * 64 + tn * 16 + m16;
            int p = quad ^ ((row >> 1) & 3);
            bf[tn] = *(const bf16x8*)&b_t[cur][row * BK + p * 8];
        }
        __builtin_amdgcn_sched_barrier(0);       // keep reads/STAGE above MFMAs

        __builtin_amdgcn_s_setprio(1);
#pragma unroll
        for (int tm = 0; tm < 4; ++tm)
#pragma unroll
            for (int tn = 0; tn < 4; ++tn)
                acc[tm][tn] = __builtin_amdgcn_mfma_f32_16x16x32_bf16(
                    af[tm], bf[tn], acc[tm][tn], 0, 0, 0);
        __builtin_amdgcn_s_setprio(0);
    }

    // ---- epilogue: d = sq_i + sq_j - 2 dot, clamp, e + e^2 + e^4 + e^8 + e^16 ----
    float ls[4] = {0.f, 0.f, 0.f, 0.f};
    if (!straddle) {
#pragma unroll
        for (int tm = 0; tm < 4; ++tm) {
            const int i0 = wm2 * 64 + tm * 16 + quad * 4;
            float sqi[4] = {sqa[i0 + 0], sqa[i0 + 1], sqa[i0 + 2], sqa[i0 + 3]};
#pragma unroll
            for (int tn = 0; tn < 4; ++tn) {
                const int j = wn2 * 64 + tn * 16 + m16;
                const float sqj = sqb[j];
#pragma unroll
                for (int rr = 0; rr < 4; ++rr) {
                    float d = fmaf(-2.f, acc[tm][tn][rr], sqi[rr] + sqj);
                    d = fmaxf(d, 0.f);
                    float e1 = __expf(-d * g0);
                    float e2 = e1 * e1, e4 = e2 * e2, e8 = e4 * e4, e16 = e8 * e8;
                    ls[rr] += e1 + e2 + e4 + e8 + e16;
                }
            }
        }
    } else {
        // diagonal-straddling tile: per-element weight 2 (above diag),
        // 1 (diagonal), 0 (below diag). Block sign is + (always same-side).
        const int dOff = (J - 2 * I) * TN;   // rowB0 - rowA0 in {0, 128}
#pragma unroll
        for (int tm = 0; tm < 4; ++tm) {
            const int i0 = wm2 * 64 + tm * 16 + quad * 4;
            float sqi[4] = {sqa[i0 + 0], sqa[i0 + 1], sqa[i0 + 2], sqa[i0 + 3]};
#pragma unroll
            for (int tn = 0; tn < 4; ++tn) {
                const int j = wn2 * 64 + tn * 16 + m16;
                const float sqj = sqb[j];
                const int jg = j + dOff;             // col in tile-row coords
#pragma unroll
                for (int rr = 0; rr < 4; ++rr) {
                    const int ig = i0 + rr;
                    float wf = (jg > ig) ? 2.f : ((jg == ig) ? 1.f : 0.f);
                    float d = fmaf(-2.f, acc[tm][tn][rr], sqi[rr] + sqj);
                    d = fmaxf(d, 0.f);
                    float e1 = __expf(-d * g0);
                    float e2 = e1 * e1, e4 = e2 * e2, e8 = e4 * e4, e16 = e8 * e8;
                    ls[rr] += wf * (e1 + e2 + e4 + e8 + e16);
                }
            }
        }
    }
    float lsum = (ls[0] + ls[1]) + (ls[2] + ls[3]);
    for (int off = 32; off; off >>= 1) lsum += __shfl_down(lsum, off);
    if (lane == 0) red[w] = lsum;
    __syncthreads();
    if (tid == 0) {
        float wgt;
        if (straddle) wgt = 1.f;                                  // per-elem weights applied
        else wgt = ((I < 16) == (J < 32)) ? 2.f : -2.f;           // mirrored tile folded in
        float scale = wgt * (1.f / NUMK) * (1.f / 16777216.f);    // /(NUMK*4096^2)
        float tot = ((red[0] + red[1]) + (red[2] + red[3]))
                  + ((red[4] + red[5]) + (red[6] + red[7]));
        atomicAdd(out, tot * scale);
    }
}

extern "C" void kernel_launch(void* const* d_in, const int* in_sizes, int n_in,
                              void* d_out, int out_size, void* d_ws, size_t ws_size,
                              hipStream_t stream) {
    const float* s_feat = (const float*)d_in[0];
    const float* t_feat = (const float*)d_in[1];
    char* ws = (char*)d_ws;
    unsigned short* fb = (unsigned short*)(ws + WS_FB);
    float* sq    = (float*)(ws + WS_SQ);
    float* pcol  = (float*)(ws + WS_PCOL);
    float* wsum  = (float*)(ws + WS_WSUM);
    float* gamma = (float*)(ws + WS_GAMMA);
    float* out   = (float*)d_out;

    void* args[] = {(void*)&s_feat, (void*)&t_feat, (void*)&fb, (void*)&sq,
                    (void*)&pcol, (void*)&wsum, (void*)&gamma, (void*)&out};
    hipLaunchCooperativeKernel((const void*)mmd_prep_fused,
                               dim3(PBLK), dim3(1024), args, 0, stream);
    mmd_main<<<NBLK, 512, 0, stream>>>(fb, sq, gamma, out);
}

// Round 16
// 101.159 us; speedup vs baseline: 1.3335x; 1.3335x over previous
//
#include <hip/hip_runtime.h>
#include <stdint.h>
#include <math.h>

// Problem constants
#define BATCH 4096
#define NT    8192          // 2*BATCH
#define FD    256           // feature dim
#define TM    256           // block tile rows (A side)
#define TN    128           // block tile cols (B side)
#define BK    32            // K chunk per staging step (8 steps, triple-buffered)
#define NUMK  5
#define NBLK  1056          // tiles (I,J) with J >= 2I; %8==0
#define PBLK  256           // prep blocks (32 rows each, 1024 threads)

typedef __attribute__((ext_vector_type(8))) short bf16x8;  // 8 bf16 = 4 VGPRs
typedef __attribute__((ext_vector_type(4))) float f32x4;

// ---- workspace layout (bytes) ----
// fb 4 MiB | sq 32 KiB | pcol 256 KiB | wsum 1 KiB | gamma 4 B
static const size_t WS_FB    = 0;
static const size_t WS_SQ    = (size_t)NT * FD * 2;              // 4194304
static const size_t WS_PCOL  = WS_SQ + (size_t)NT * 4;           // +32768
static const size_t WS_WSUM  = WS_PCOL + (size_t)PBLK * 256 * 4; // +256 KiB
static const size_t WS_GAMMA = WS_WSUM + (size_t)PBLK * 4;       // +1 KiB

__device__ __forceinline__ unsigned short f2bf_rne(float x) {
    unsigned u = __float_as_uint(x);
    unsigned r = (u + 0x7fffu + ((u >> 16) & 1u)) >> 16;
    return (unsigned short)r;
}

__device__ __forceinline__ void async_copy16(void* lds, const void* g) {
    __builtin_amdgcn_global_load_lds(
        (__attribute__((address_space(1))) void*)(void*)(const_cast<void*>(g)),
        (__attribute__((address_space(3))) void*)lds, 16, 0, 0);
}

// ---------------- kernel 1: convert + row norms + per-block partials ----------
// 256 blocks x 1024 threads (16 waves), 32 rows/block. NO atomics (r12 showed
// colsum atomics cost ~50 us). Only 256 partial rows -> gamma reads 256 KiB.
__global__ void mmd_prep(const float* __restrict__ s_feat,
                         const float* __restrict__ t_feat,
                         unsigned short* __restrict__ fb,
                         float* __restrict__ sq,
                         float* __restrict__ pcol,
                         float* __restrict__ wsum) {
    __shared__ float cp[16][FD];
    __shared__ float rw[16];
    const int w    = threadIdx.x >> 6;           // 0..15
    const int lane = threadIdx.x & 63;
    float c0 = 0.f, c1 = 0.f, c2 = 0.f, c3 = 0.f;
    float wtot = 0.f;
#pragma unroll
    for (int t = 0; t < 2; ++t) {
        int row = blockIdx.x * 32 + w * 2 + t;
        const float* src = (row < BATCH) ? (s_feat + (size_t)row * FD)
                                         : (t_feat + (size_t)(row - BATCH) * FD);
        float4 v = ((const float4*)src)[lane];
        unsigned int u01 = (unsigned)f2bf_rne(v.x) | ((unsigned)f2bf_rne(v.y) << 16);
        unsigned int u23 = (unsigned)f2bf_rne(v.z) | ((unsigned)f2bf_rne(v.w) << 16);
        ((uint2*)(fb + (size_t)row * FD))[lane] = make_uint2(u01, u23);
        float ss = v.x * v.x + v.y * v.y + v.z * v.z + v.w * v.w;
        for (int off = 32; off; off >>= 1) ss += __shfl_down(ss, off);
        if (lane == 0) { sq[row] = ss; wtot += ss; }
        c0 += v.x; c1 += v.y; c2 += v.z; c3 += v.w;
    }
    cp[w][4 * lane + 0] = c0;
    cp[w][4 * lane + 1] = c1;
    cp[w][4 * lane + 2] = c2;
    cp[w][4 * lane + 3] = c3;
    if (lane == 0) rw[w] = wtot;
    __syncthreads();
    const int t = threadIdx.x;
    if (t < 256) {
        float s = 0.f;
#pragma unroll
        for (int k = 0; k < 16; ++k) s += cp[k][t];
        pcol[(size_t)blockIdx.x * 256 + t] = s;
    }
    if (t == 0) {
        float s = 0.f;
#pragma unroll
        for (int k = 0; k < 16; ++k) s += rw[k];
        wsum[blockIdx.x] = s;
    }
}

// ---------------- kernel 2: reduce 256 KiB partials -> gamma0; zero out --------
__global__ void mmd_gamma(const float* __restrict__ pcol,
                          const float* __restrict__ wsum,
                          float* __restrict__ gamma,
                          float* __restrict__ out) {
    __shared__ float gcol[4][256];
    __shared__ float redc[4], redw[4];
    const int tid  = threadIdx.x;        // 1024 threads
    const int c    = tid & 255, s = tid >> 8;    // s = 0..3
    const int lane = tid & 63;
    float a0 = 0.f, a1 = 0.f, a2 = 0.f, a3 = 0.f;
#pragma unroll 4
    for (int k = 0; k < 64; k += 4) {
        a0 += pcol[(size_t)(s * 64 + k + 0) * 256 + c];
        a1 += pcol[(size_t)(s * 64 + k + 1) * 256 + c];
        a2 += pcol[(size_t)(s * 64 + k + 2) * 256 + c];
        a3 += pcol[(size_t)(s * 64 + k + 3) * 256 + c];
    }
    gcol[s][c] = (a0 + a1) + (a2 + a3);
    if (tid < 256) {
        float wv = wsum[tid];
        for (int off = 32; off; off >>= 1) wv += __shfl_down(wv, off);
        if (lane == 0) redw[tid >> 6] = wv;
    }
    __syncthreads();
    if (tid < 256) {
        float colv = (gcol[0][c] + gcol[1][c]) + (gcol[2][c] + gcol[3][c]);
        float cv2 = colv * colv;
        for (int off = 32; off; off >>= 1) cv2 += __shfl_down(cv2, off);
        if (lane == 0) redc[tid >> 6] = cv2;
    }
    __syncthreads();
    if (tid == 0) {
        float s2  = (redc[0] + redc[1]) + (redc[2] + redc[3]);
        float ssq = (redw[0] + redw[1]) + (redw[2] + redw[3]);
        // sum(distances) = 2*n*sum(sq) - 2*||colsum||^2 (clamp effect negligible)
        float sumd = 2.0f * (float)NT * ssq - 2.0f * s2;
        float n2n  = (float)((long long)NT * NT - NT);   // n^2 - n
        gamma[0]   = 0.25f * (n2n / sumd);   // bw / 2^(NUM_KERNELS//2)
        out[0]     = 0.f;                    // zero accumulator for mmd_main
    }
}

// ---------------- kernel 3: fused GEMM + gaussian-kernel + reduce ----------------
// Champion (r8/r13), verbatim: 256x128 tiles, 512 threads (8 waves, 4Mx2N);
// triple-buffered BK=32 with counted vmcnt; gamma read as precomputed scalar.
__global__ __launch_bounds__(512, 4) void mmd_main(
    const unsigned short* __restrict__ fb,
    const float* __restrict__ sq,
    const float* __restrict__ gamma,
    float* __restrict__ out) {
    // XCD-chunked swizzle (NBLK % 8 == 0 -> bijective)
    const int bid = blockIdx.x;
    const int swz = (bid & 7) * (NBLK / 8) + (bid >> 3);
    // decode: I = largest i with C(i)=i*(65-i) <= swz ; J = 2I + (swz - C(I))
    int I = (int)((65.0f - sqrtf(fmaxf(4225.0f - 4.0f * (float)swz, 0.f))) * 0.5f);
    if (I > 31) I = 31;
    while (I > 0 && I * (65 - I) > swz) --I;
    while (I < 31 && (I + 1) * (65 - (I + 1)) <= swz) ++I;
    const int J = 2 * I + (swz - I * (65 - I));
    const bool straddle = ((J >> 1) == I);   // tile touches the diagonal

    __shared__ __align__(16) unsigned short a_t[3][TM * BK];  // 3 x 16 KiB
    __shared__ __align__(16) unsigned short b_t[3][TN * BK];  // 3 x 8 KiB
    __shared__ float sqa[TM], sqb[TN];
    __shared__ float red[8];

    const int tid  = threadIdx.x;
    const int w    = tid >> 6, lane = tid & 63;
    const int wm2  = w >> 1, wn2 = w & 1;        // 4x2 waves over 256x128
    const int quad = lane >> 4, m16 = lane & 15;
    const int lrow16 = lane >> 2;                // 0..15 (row within 16-row group)
    const int pslot  = lane & 3;                 // physical 16B slot within 64B row

    const size_t rowA0 = (size_t)I * TM;
    const size_t rowB0 = (size_t)J * TN;

    // oldest loads first: sq + gamma (consumed pre-loop)
    float sqv = 0.f;
    if (tid < TM)                sqv = sq[rowA0 + tid];
    else if (tid < TM + TN)      sqv = sq[rowB0 + (tid - TM)];
    const float g0 = gamma[0];

    // Swizzle: physical slot p of row r holds global chunk p ^ ((r>>1)&3).
#define STAGE(buf, k0_) do {                                                   \
        _Pragma("unroll")                                                      \
        for (int q = 0; q < 2; ++q) {                                          \
            int rr_ = w * 32 + q * 16 + lrow16;   /* 0..255 */                 \
            int gc_ = pslot ^ ((rr_ >> 1) & 3);                                \
            async_copy16(&a_t[buf][(w * 32 + q * 16) * BK],                    \
                         fb + (rowA0 + rr_) * FD + (k0_) + gc_ * 8);           \
        }                                                                      \
        {                                                                      \
            int rr_ = w * 16 + lrow16;            /* 0..127 */                 \
            int gc_ = pslot ^ ((rr_ >> 1) & 3);                                \
            async_copy16(&b_t[buf][(w * 16) * BK],                             \
                         fb + (rowB0 + rr_) * FD + (k0_) + gc_ * 8);           \
        }                                                                      \
    } while (0)

    // prologue: fill buffers 0..2 (drained by the single __syncthreads below)
    STAGE(0, 0);
    STAGE(1, BK);
    STAGE(2, 2 * BK);

    if (tid < TM)                sqa[tid] = sqv;
    else if (tid < TM + TN)      sqb[tid - TM] = sqv;

    const f32x4 fzero = {0.f, 0.f, 0.f, 0.f};
    f32x4 acc[4][4];
#pragma unroll
    for (int a = 0; a < 4; ++a)
#pragma unroll
        for (int b = 0; b < 4; ++b) acc[a][b] = fzero;

    __syncthreads();   // full drain once: chunks 0-2 resident, sqa/sqb visible

#pragma unroll
    for (int st = 0; st < 8; ++st) {
        if (st > 0) {
            if (st >= 3) {
                // certify chunk st (staged at step st-2); keep st-1's 3 loads
                // in flight. At st=7 nothing newer is outstanding.
                if (st == 7) asm volatile("s_waitcnt vmcnt(0)" ::: "memory");
                else         asm volatile("s_waitcnt vmcnt(3)" ::: "memory");
            }
            __builtin_amdgcn_s_barrier();        // publish buf; frees buf (st-1)%3
            __builtin_amdgcn_sched_barrier(0);
            // stage chunk st+2 into the buffer freed by this barrier
            if (st <= 5) STAGE((st + 2) % 3, (st + 2) * BK);
        }
        const int cur = st % 3;   // compile-time after full unroll

        bf16x8 af[4], bf[4];
#pragma unroll
        for (int tm = 0; tm < 4; ++tm) {
            int row = wm2 * 64 + tm * 16 + m16;
            int p = quad ^ ((row >> 1) & 3);
            af[tm] = *(const bf16x8*)&a_t[cur][row * BK + p * 8];
        }
#pragma unroll
        for (int tn = 0; tn < 4; ++tn) {
            int row = wn2 * 64 + tn * 16 + m16;
            int p = quad ^ ((row >> 1) & 3);
            bf[tn] = *(const bf16x8*)&b_t[cur][row * BK + p * 8];
        }
        __builtin_amdgcn_sched_barrier(0);       // keep reads/STAGE above MFMAs

        __builtin_amdgcn_s_setprio(1);
#pragma unroll
        for (int tm = 0; tm < 4; ++tm)
#pragma unroll
            for (int tn = 0; tn < 4; ++tn)
                acc[tm][tn] = __builtin_amdgcn_mfma_f32_16x16x32_bf16(
                    af[tm], bf[tn], acc[tm][tn], 0, 0, 0);
        __builtin_amdgcn_s_setprio(0);
    }

    // ---- epilogue: d = sq_i + sq_j - 2 dot, clamp, e + e^2 + e^4 + e^8 + e^16 ----
    float ls[4] = {0.f, 0.f, 0.f, 0.f};
    if (!straddle) {
#pragma unroll
        for (int tm = 0; tm < 4; ++tm) {
            const int i0 = wm2 * 64 + tm * 16 + quad * 4;
            float sqi[4] = {sqa[i0 + 0], sqa[i0 + 1], sqa[i0 + 2], sqa[i0 + 3]};
#pragma unroll
            for (int tn = 0; tn < 4; ++tn) {
                const int j = wn2 * 64 + tn * 16 + m16;
                const float sqj = sqb[j];
#pragma unroll
                for (int rr = 0; rr < 4; ++rr) {
                    float d = fmaf(-2.f, acc[tm][tn][rr], sqi[rr] + sqj);
                    d = fmaxf(d, 0.f);
                    float e1 = __expf(-d * g0);
                    float e2 = e1 * e1, e4 = e2 * e2, e8 = e4 * e4, e16 = e8 * e8;
                    ls[rr] += e1 + e2 + e4 + e8 + e16;
                }
            }
        }
    } else {
        // diagonal-straddling tile: per-element weight 2 (above diag),
        // 1 (diagonal), 0 (below diag). Block sign is + (always same-side).
        const int dOff = (J - 2 * I) * TN;   // rowB0 - rowA0 in {0, 128}
#pragma unroll
        for (int tm = 0; tm < 4; ++tm) {
            const int i0 = wm2 * 64 + tm * 16 + quad * 4;
            float sqi[4] = {sqa[i0 + 0], sqa[i0 + 1], sqa[i0 + 2], sqa[i0 + 3]};
#pragma unroll
            for (int tn = 0; tn < 4; ++tn) {
                const int j = wn2 * 64 + tn * 16 + m16;
                const float sqj = sqb[j];
                const int jg = j + dOff;             // col in tile-row coords
#pragma unroll
                for (int rr = 0; rr < 4; ++rr) {
                    const int ig = i0 + rr;
                    float wf = (jg > ig) ? 2.f : ((jg == ig) ? 1.f : 0.f);
                    float d = fmaf(-2.f, acc[tm][tn][rr], sqi[rr] + sqj);
                    d = fmaxf(d, 0.f);
                    float e1 = __expf(-d * g0);
                    float e2 = e1 * e1, e4 = e2 * e2, e8 = e4 * e4, e16 = e8 * e8;
                    ls[rr] += wf * (e1 + e2 + e4 + e8 + e16);
                }
            }
        }
    }
    float lsum = (ls[0] + ls[1]) + (ls[2] + ls[3]);
    for (int off = 32; off; off >>= 1) lsum += __shfl_down(lsum, off);
    if (lane == 0) red[w] = lsum;
    __syncthreads();
    if (tid == 0) {
        float wgt;
        if (straddle) wgt = 1.f;                                  // per-elem weights applied
        else wgt = ((I < 16) == (J < 32)) ? 2.f : -2.f;           // mirrored tile folded in
        float scale = wgt * (1.f / NUMK) * (1.f / 16777216.f);    // /(NUMK*4096^2)
        float tot = ((red[0] + red[1]) + (red[2] + red[3]))
                  + ((red[4] + red[5]) + (red[6] + red[7]));
        atomicAdd(out, tot * scale);
    }
}

extern "C" void kernel_launch(void* const* d_in, const int* in_sizes, int n_in,
                              void* d_out, int out_size, void* d_ws, size_t ws_size,
                              hipStream_t stream) {
    const float* s_feat = (const float*)d_in[0];
    const float* t_feat = (const float*)d_in[1];
    char* ws = (char*)d_ws;
    unsigned short* fb = (unsigned short*)(ws + WS_FB);
    float* sq    = (float*)(ws + WS_SQ);
    float* pcol  = (float*)(ws + WS_PCOL);
    float* wsum  = (float*)(ws + WS_WSUM);
    float* gamma = (float*)(ws + WS_GAMMA);
    float* out   = (float*)d_out;

    mmd_prep<<<PBLK, 1024, 0, stream>>>(s_feat, t_feat, fb, sq, pcol, wsum);
    mmd_gamma<<<1, 1024, 0, stream>>>(pcol, wsum, gamma, out);
    mmd_main<<<NBLK, 512, 0, stream>>>(fb, sq, gamma, out);
}